// Round 14
// baseline (86.132 us; speedup 1.0000x reference)
//
#include <hip/hip_runtime.h>
#include <math.h>

// contracting REN forward. S=8, N=64, NU=6, NY=5, NH=80, B=524288.
// Outputs: hidden (B,8) then y (B,5), concatenated flat.
// R14: v_pk_fma_f32 (f32x2) scatter-form scan, 1 row/thread, plain loops,
// launch_bounds(256) (R1/R9-proven register-promotion shape). All f32.

constexpr int NH = 80;

// ---- workspace layout (float word offsets; pair bases even) ----
constexpr int WS_DT2  = 0;      // [64 j][32 p] f32x2: (kDt[2p][j], kDt[2p+1][j]), 0 for i<=j
constexpr int WS_V0C2 = 4096;   // [14 c][32 p] f32x2: v0 coefs (C1f c<8, D12f c>=8), kappa-scaled
constexpr int WS_BWF  = 4992;   // [64] kappa*bw/Lambda (pairs = linear)
constexpr int WS_G2   = 5056;   // [8 a][64 j] Einv@B1, a-major (pairs = linear)
constexpr int WS_D21  = 5568;   // [5 q][64 j] D21 copy (pairs = linear)
constexpr int WS_G1   = 5888;   // [8][8]  Einv@F_
constexpr int WS_G3   = 5952;   // [8][6]  Einv@calB_2
constexpr int WS_G4   = 6000;   // [8]     Einv@bx
constexpr int WS_C2W  = 6008;   // [5][8]  C2 copy
constexpr int WS_D22W = 6048;   // [5][6]  D22 copy
constexpr int WS_BY   = 6078;   // [5]     by
// prep scratch
constexpr int WS_H    = 8192;   // [80][80]

typedef float f32x2 __attribute__((ext_vector_type(2)));

__global__ void k_gram(const float* __restrict__ X, float* __restrict__ ws) {
    int idx = blockIdx.x * blockDim.x + threadIdx.x;
    if (idx >= NH * NH) return;
    int a = idx / NH, b = idx % NH;
    float acc = (a == b) ? 1e-4f : 0.f;
    for (int k = 0; k < NH; k++) acc += X[k * NH + a] * X[k * NH + b];
    ws[WS_H + idx] = acc;
}

// fused: 8x8 Gauss-Jordan (LDS) + all constant folding. One block, 256 thr.
__global__ void k_prep(const float* __restrict__ calB2,
                       const float* __restrict__ calD12,
                       const float* __restrict__ C2,
                       const float* __restrict__ D21,
                       const float* __restrict__ D22,
                       const float* __restrict__ Y1,
                       const float* __restrict__ bias,
                       float* __restrict__ ws) {
    __shared__ float sM[8][17];
    __shared__ int sPiv;
    __shared__ float srL[64];
    __shared__ float sEinv[64];
    int tid = threadIdx.x;  // 256
    const float* H = ws + WS_H;
    const float KAPPA = 2.8853900817779268f;  // 2*log2(e)

    if (tid < 128) {
        int r = tid >> 4, c = tid & 15;
        sM[r][c] = (c < 8)
            ? 0.5f * (H[r * NH + c] + H[(72 + r) * NH + 72 + c] + Y1[r * 8 + c])
            : ((c - 8 == r) ? 1.f : 0.f);
    }
    if (tid >= 128 && tid < 192) srL[tid - 128] = 2.0f / H[(8 + tid - 128) * NH + 8 + tid - 128];
    __syncthreads();

    for (int p = 0; p < 8; p++) {
        if (tid == 0) {
            int pr = p; float best = fabsf(sM[p][p]);
            for (int r = p + 1; r < 8; r++) {
                float v = fabsf(sM[r][p]);
                if (v > best) { best = v; pr = r; }
            }
            sPiv = pr;
        }
        __syncthreads();
        int pr = sPiv;
        if (pr != p && tid < 16) { float tv = sM[p][tid]; sM[p][tid] = sM[pr][tid]; sM[pr][tid] = tv; }
        __syncthreads();
        if (tid < 16) {   // single wave: all lanes read pivot before any write
            float inv = 1.f / sM[p][p];
            sM[p][tid] *= inv;
        }
        __syncthreads();
        float f = 0.f, pc = 0.f;
        if (tid < 128) { int r = tid >> 4, c = tid & 15; f = sM[r][p]; pc = sM[p][c]; }
        __syncthreads();
        if (tid < 128) { int r = tid >> 4, c = tid & 15; if (r != p) sM[r][c] -= f * pc; }
        __syncthreads();
    }
    if (tid < 64) sEinv[tid] = sM[tid >> 3][8 + (tid & 7)];
    __syncthreads();

    // DT2: j-major pairs of i. idx = j*32+p
    for (int idx = tid; idx < 2048; idx += 256) {
        int j = idx >> 5, p = idx & 31;
        int i0 = 2 * p, i1 = 2 * p + 1;
        float f0 = (i0 > j) ? -KAPPA * H[(8 + i0) * NH + 8 + j] * srL[i0] : 0.f;
        float f1 = (i1 > j) ? -KAPPA * H[(8 + i1) * NH + 8 + j] * srL[i1] : 0.f;
        ws[WS_DT2 + 2 * idx]     = f0;
        ws[WS_DT2 + 2 * idx + 1] = f1;
    }
    // V0C2: c-major pairs of i. idx = c*32+p ; c<8 -> C1f, c>=8 -> D12f
    for (int idx = tid; idx < 448; idx += 256) {
        int c = idx >> 5, p = idx & 31;
        int i0 = 2 * p, i1 = 2 * p + 1;
        float f0, f1;
        if (c < 8) {
            f0 = -KAPPA * H[(8 + i0) * NH + c] * srL[i0];
            f1 = -KAPPA * H[(8 + i1) * NH + c] * srL[i1];
        } else {
            f0 = KAPPA * calD12[i0 * 6 + (c - 8)] * srL[i0];
            f1 = KAPPA * calD12[i1 * 6 + (c - 8)] * srL[i1];
        }
        ws[WS_V0C2 + 2 * idx]     = f0;
        ws[WS_V0C2 + 2 * idx + 1] = f1;
    }
    if (tid < 64) ws[WS_BWF + tid] = KAPPA * bias[8 + tid] * srL[tid];
    // G2 a-major (Einv@B1)
    for (int idx = tid; idx < 512; idx += 256) {
        int a = idx >> 6, j = idx & 63; float acc = 0.f;
        for (int k = 0; k < 8; k++) acc += sEinv[a * 8 + k] * H[(72 + k) * NH + 8 + j];
        ws[WS_G2 + idx] = acc;
    }
    // D21 copy q-major
    for (int idx = tid; idx < 320; idx += 256) ws[WS_D21 + idx] = D21[idx];
    // G1 = Einv@F_
    if (tid < 64) {
        int a = tid >> 3, s = tid & 7; float acc = 0.f;
        for (int k = 0; k < 8; k++) acc += sEinv[a * 8 + k] * H[(72 + k) * NH + s];
        ws[WS_G1 + tid] = acc;
    }
    // G3 = Einv@calB_2
    if (tid < 48) {
        int a = tid / 6, c = tid % 6; float acc = 0.f;
        for (int k = 0; k < 8; k++) acc += sEinv[a * 8 + k] * calB2[k * 6 + c];
        ws[WS_G3 + tid] = acc;
    }
    // g4 = Einv@bx
    if (tid < 8) {
        float acc = 0.f;
        for (int k = 0; k < 8; k++) acc += sEinv[tid * 8 + k] * bias[k];
        ws[WS_G4 + tid] = acc;
    }
    if (tid < 40) ws[WS_C2W + tid]  = C2[tid];
    if (tid < 30) ws[WS_D22W + tid] = D22[tid];
    if (tid < 5)  ws[WS_BY + tid]   = bias[72 + tid];
}

// acc already kappa-scaled: tanh(v) = 1 - 2/(1+2^q). No clamp needed:
// exp2(+big)=inf -> rcp=0 -> +1 ; exp2(-big)=0 -> rcp(1)=1 -> -1.
__device__ __forceinline__ float tanh_scaled(float q) {
    float e = __builtin_amdgcn_exp2f(q);
    return 1.f - 2.f * __builtin_amdgcn_rcpf(1.f + e);
}

__global__ __launch_bounds__(256) void k_main(
    const float* __restrict__ xg, const float* __restrict__ ug,
    const float* __restrict__ ws, float* __restrict__ out, int B)
{
    int t = blockIdx.x * blockDim.x + threadIdx.x;
    if (t >= B) return;

    float xu[14];
    {
        const float4* xp = reinterpret_cast<const float4*>(xg + (size_t)t * 8);
        float4 a0 = xp[0], a1 = xp[1];
        xu[0]=a0.x; xu[1]=a0.y; xu[2]=a0.z; xu[3]=a0.w;
        xu[4]=a1.x; xu[5]=a1.y; xu[6]=a1.z; xu[7]=a1.w;
        const float2* up = reinterpret_cast<const float2*>(ug + (size_t)t * 6);
        float2 c0 = up[0], c1 = up[1], c2 = up[2];
        xu[8]=c0.x; xu[9]=c0.y; xu[10]=c1.x; xu[11]=c1.y; xu[12]=c2.x; xu[13]=c2.y;
    }

    const f32x2* DT2  = reinterpret_cast<const f32x2*>(ws + WS_DT2);
    const f32x2* V0C  = reinterpret_cast<const f32x2*>(ws + WS_V0C2);
    const f32x2* BW2  = reinterpret_cast<const f32x2*>(ws + WS_BWF);
    const f32x2* G2P  = reinterpret_cast<const f32x2*>(ws + WS_G2);
    const f32x2* D21P = reinterpret_cast<const f32x2*>(ws + WS_D21);

    // v0 (kappa-scaled), packed pairs of neurons; scatter over inputs.
    f32x2 v2[32];
    #pragma unroll
    for (int p = 0; p < 32; p++) v2[p] = BW2[p];
    #pragma unroll
    for (int c = 0; c < 14; c++) {
        f32x2 bc = { xu[c], xu[c] };
        #pragma unroll
        for (int p = 0; p < 32; p++)
            v2[p] = __builtin_elementwise_fma(V0C[c * 32 + p], bc, v2[p]);
    }

    // x/u parts of outputs (scalar f32)
    float h[8];
    #pragma unroll
    for (int a = 0; a < 8; a++) {
        float acc = ws[WS_G4 + a];
        #pragma unroll
        for (int s = 0; s < 8; s++) acc += xu[s] * ws[WS_G1 + a * 8 + s];
        #pragma unroll
        for (int c = 0; c < 6; c++) acc += xu[8 + c] * ws[WS_G3 + a * 6 + c];
        h[a] = acc;
    }
    float y[5];
    #pragma unroll
    for (int q = 0; q < 5; q++) {
        float acc = ws[WS_BY + q];
        #pragma unroll
        for (int s = 0; s < 8; s++) acc += xu[s] * ws[WS_C2W + q * 8 + s];
        #pragma unroll
        for (int c = 0; c < 6; c++) acc += xu[8 + c] * ws[WS_D22W + q * 6 + c];
        y[q] = acc;
    }

    // scatter-form triangular tanh scan on packed pairs.
    // At step j: tanh v[j] (write w back into its own VGPR), then
    // v2[p] += DT2[j][p] * (wj,wj) for all pairs with an i>j component.
    // Diagonal/below-diagonal coefficients are 0, so updates are uniform.
    #pragma unroll
    for (int j = 0; j < 64; j++) {
        float vj = (j & 1) ? v2[j >> 1].y : v2[j >> 1].x;
        float wj = tanh_scaled(vj);
        if (j & 1) v2[j >> 1].y = wj; else v2[j >> 1].x = wj;
        f32x2 wb = { wj, wj };
        #pragma unroll
        for (int p = (j >> 1) + (j & 1); p < 32; p++)
            v2[p] = __builtin_elementwise_fma(DT2[j * 32 + p], wb, v2[p]);
    }

    // w contributions to outputs (v2 now holds w pairs)
    #pragma unroll
    for (int a = 0; a < 8; a++) {
        f32x2 acc = { h[a], 0.f };
        #pragma unroll
        for (int p = 0; p < 32; p++)
            acc = __builtin_elementwise_fma(G2P[a * 32 + p], v2[p], acc);
        h[a] = acc.x + acc.y;
    }
    float4* hp = reinterpret_cast<float4*>(out + (size_t)t * 8);
    hp[0] = make_float4(h[0], h[1], h[2], h[3]);
    hp[1] = make_float4(h[4], h[5], h[6], h[7]);

    float* yp = out + (size_t)B * 8 + (size_t)t * 5;
    #pragma unroll
    for (int q = 0; q < 5; q++) {
        f32x2 acc = { y[q], 0.f };
        #pragma unroll
        for (int p = 0; p < 32; p++)
            acc = __builtin_elementwise_fma(D21P[q * 32 + p], v2[p], acc);
        yp[q] = acc.x + acc.y;
    }
}

extern "C" void kernel_launch(void* const* d_in, const int* in_sizes, int n_in,
                              void* d_out, int out_size, void* d_ws, size_t ws_size,
                              hipStream_t stream) {
    const float* x      = (const float*)d_in[0];
    const float* u      = (const float*)d_in[1];
    const float* X      = (const float*)d_in[2];
    const float* calB2  = (const float*)d_in[3];
    const float* C2     = (const float*)d_in[4];
    const float* calD12 = (const float*)d_in[5];
    const float* D21    = (const float*)d_in[6];
    const float* D22    = (const float*)d_in[7];
    const float* Y1     = (const float*)d_in[8];
    const float* bias   = (const float*)d_in[9];
    float* ws  = (float*)d_ws;
    float* out = (float*)d_out;
    int B = in_sizes[0] / 8;

    k_gram<<<(NH * NH + 255) / 256, 256, 0, stream>>>(X, ws);
    k_prep<<<1, 256, 0, stream>>>(calB2, calD12, C2, D21, D22, Y1, bias, ws);
    k_main<<<(B + 255) / 256, 256, 0, stream>>>(x, u, ws, out, B);
}

// Round 15
// 71.936 us; speedup vs baseline: 1.1974x; 1.1974x over previous
//
#include <hip/hip_runtime.h>
#include <hip/hip_fp16.h>
#include <math.h>

// contracting REN forward. S=8, N=64, NU=6, NY=5, NH=80, B=524288.
// Outputs: hidden (B,8) then y (B,5), concatenated flat.
// R15 = R12 structure (f16 pairs + v_dot2_f32_f16, dual-accum scan)
//       x 2 rows/thread (ILP), + gram fused into the prep kernel.

constexpr int NH = 80;

// ---- workspace layout (uint word offsets) ----
constexpr int WS_DTT2 = 0;      // uint[64*32]  kappa*Dt[i] packed pairs (j<i else 0)
constexpr int WS_V0C  = 2048;   // uint[64*8]   per i: 4 C1 pairs, 3 D12 pairs, 1 zero
constexpr int WS_G2P  = 2560;   // uint[8*32]   (Einv@B1)[a] packed pairs
constexpr int WS_D21P = 2816;   // uint[5*32]   D21[q] packed pairs
constexpr int WS_G1P  = 2976;   // uint[8*4]    (Einv@F_)[a] packed pairs
constexpr int WS_G3P  = 3008;   // uint[8*3]    (Einv@calB_2)[a] packed pairs
constexpr int WS_C2P  = 3032;   // uint[5*4]    C2[q] packed pairs
constexpr int WS_D22P = 3052;   // uint[5*3]    D22[q] packed pairs
// float-valued words
constexpr int WS_BWF  = 3072;   // float[64]    kappa*bw/Lambda
constexpr int WS_G4   = 3136;   // float[8]     Einv@bx
constexpr int WS_BY   = 3144;   // float[5]     by

__device__ __forceinline__ unsigned pack_rn(float a, float b) {
    unsigned lo = __half_as_ushort(__float2half(a));
    unsigned hi = __half_as_ushort(__float2half(b));
    return lo | (hi << 16);
}

typedef _Float16 h2 __attribute__((ext_vector_type(2)));

__device__ __forceinline__ float dot2(unsigned c, unsigned w, float acc) {
#if __has_builtin(__builtin_amdgcn_fdot2)
    return __builtin_amdgcn_fdot2(__builtin_bit_cast(h2, c),
                                  __builtin_bit_cast(h2, w), acc, false);
#else
    float out;
    asm("v_dot2_f32_f16 %0, %1, %2, %3" : "=v"(out) : "v"(c), "v"(w), "0"(acc));
    return out;
#endif
}
__device__ __forceinline__ float lo_f(unsigned u) { return (float)__builtin_bit_cast(h2, u).x; }

// single fused prep: stage X -> gram in LDS -> Gauss-Jordan -> fold+pack all constants.
__global__ __launch_bounds__(512) void k_prep(
    const float* __restrict__ X,
    const float* __restrict__ calB2,
    const float* __restrict__ calD12,
    const float* __restrict__ C2,
    const float* __restrict__ D21,
    const float* __restrict__ D22,
    const float* __restrict__ Y1,
    const float* __restrict__ bias,
    float* ws)
{
    __shared__ float sX[NH * NH];
    __shared__ float sH[NH * NH];
    __shared__ float sM[8][17];
    __shared__ int sPiv;
    __shared__ float srL[64];
    __shared__ float sEinv[64];
    int tid = threadIdx.x;  // 512
    unsigned* wsu = (unsigned*)ws;
    const float KAPPA = 2.8853900817779268f;  // 2*log2(e)

    // stage X
    for (int i = tid; i < NH * NH / 4; i += 512)
        reinterpret_cast<float4*>(sX)[i] = reinterpret_cast<const float4*>(X)[i];
    __syncthreads();

    // gram H = X^T X + eps*I, 2x2 tiles
    for (int idx = tid; idx < 1600; idx += 512) {
        int ta = idx / 40, tb = idx % 40;
        int a0 = 2 * ta, b0 = 2 * tb;
        float s00 = 0.f, s01 = 0.f, s10 = 0.f, s11 = 0.f;
        for (int k = 0; k < NH; k++) {
            float xa0 = sX[k * NH + a0], xa1 = sX[k * NH + a0 + 1];
            float xb0 = sX[k * NH + b0], xb1 = sX[k * NH + b0 + 1];
            s00 += xa0 * xb0; s01 += xa0 * xb1;
            s10 += xa1 * xb0; s11 += xa1 * xb1;
        }
        if (a0 == b0) { s00 += 1e-4f; s11 += 1e-4f; }
        sH[a0 * NH + b0] = s00; sH[a0 * NH + b0 + 1] = s01;
        sH[(a0 + 1) * NH + b0] = s10; sH[(a0 + 1) * NH + b0 + 1] = s11;
    }
    __syncthreads();

    if (tid < 128) {
        int r = tid >> 4, c = tid & 15;
        sM[r][c] = (c < 8)
            ? 0.5f * (sH[r * NH + c] + sH[(72 + r) * NH + 72 + c] + Y1[r * 8 + c])
            : ((c - 8 == r) ? 1.f : 0.f);
    }
    if (tid >= 128 && tid < 192) srL[tid - 128] = 2.0f / sH[(8 + tid - 128) * NH + 8 + tid - 128];
    __syncthreads();

    for (int p = 0; p < 8; p++) {
        if (tid == 0) {
            int pr = p; float best = fabsf(sM[p][p]);
            for (int r = p + 1; r < 8; r++) {
                float v = fabsf(sM[r][p]);
                if (v > best) { best = v; pr = r; }
            }
            sPiv = pr;
        }
        __syncthreads();
        int pr = sPiv;
        if (pr != p && tid < 16) { float tv = sM[p][tid]; sM[p][tid] = sM[pr][tid]; sM[pr][tid] = tv; }
        __syncthreads();
        if (tid < 16) {   // single wave: all lanes read pivot before any write
            float inv = 1.f / sM[p][p];
            sM[p][tid] *= inv;
        }
        __syncthreads();
        float f = 0.f, pc = 0.f;
        if (tid < 128) { int r = tid >> 4, c = tid & 15; f = sM[r][p]; pc = sM[p][c]; }
        __syncthreads();
        if (tid < 128) { int r = tid >> 4, c = tid & 15; if (r != p) sM[r][c] -= f * pc; }
        __syncthreads();
    }
    if (tid < 64) sEinv[tid] = sM[tid >> 3][8 + (tid & 7)];
    __syncthreads();

    // DTT2: packed kappa-scaled Dt rows (j<i else 0)
    for (int idx = tid; idx < 2048; idx += 512) {
        int i = idx >> 5, p = idx & 31;
        int j0 = 2 * p, j1 = 2 * p + 1;
        float f0 = (j0 < i) ? -KAPPA * sH[(8 + i) * NH + 8 + j0] * srL[i] : 0.f;
        float f1 = (j1 < i) ? -KAPPA * sH[(8 + i) * NH + 8 + j1] * srL[i] : 0.f;
        wsu[WS_DTT2 + idx] = pack_rn(f0, f1);
    }
    // V0C: per-row packed C1 (4 pairs) + D12 (3 pairs) + zero
    if (tid < 512) {
        int i = tid >> 3, c = tid & 7;
        float f0 = 0.f, f1 = 0.f;
        if (c < 4) {
            f0 = -KAPPA * sH[(8 + i) * NH + 2 * c] * srL[i];
            f1 = -KAPPA * sH[(8 + i) * NH + 2 * c + 1] * srL[i];
        } else if (c < 7) {
            int d = 2 * (c - 4);
            f0 = KAPPA * calD12[i * 6 + d] * srL[i];
            f1 = KAPPA * calD12[i * 6 + d + 1] * srL[i];
        }
        wsu[WS_V0C + tid] = pack_rn(f0, f1);
    }
    // G2P = packed (Einv @ B1)
    if (tid < 256) {
        int a = tid >> 5, p = tid & 31;
        float g0 = 0.f, g1 = 0.f;
        for (int k = 0; k < 8; k++) {
            g0 += sEinv[a * 8 + k] * sH[(72 + k) * NH + 8 + 2 * p];
            g1 += sEinv[a * 8 + k] * sH[(72 + k) * NH + 8 + 2 * p + 1];
        }
        wsu[WS_G2P + tid] = pack_rn(g0, g1);
    }
    // D21P packed
    if (tid < 160) {
        int q = tid / 32, p = tid % 32;
        wsu[WS_D21P + tid] = pack_rn(D21[q * 64 + 2 * p], D21[q * 64 + 2 * p + 1]);
    }
    // G1P = packed (Einv @ F_)
    if (tid < 32) {
        int a = tid >> 2, c = tid & 3;
        float g0 = 0.f, g1 = 0.f;
        for (int k = 0; k < 8; k++) {
            g0 += sEinv[a * 8 + k] * sH[(72 + k) * NH + 2 * c];
            g1 += sEinv[a * 8 + k] * sH[(72 + k) * NH + 2 * c + 1];
        }
        wsu[WS_G1P + tid] = pack_rn(g0, g1);
    }
    // G3P = packed (Einv @ calB_2)
    if (tid < 24) {
        int a = tid / 3, c = tid % 3;
        float g0 = 0.f, g1 = 0.f;
        for (int k = 0; k < 8; k++) {
            g0 += sEinv[a * 8 + k] * calB2[k * 6 + 2 * c];
            g1 += sEinv[a * 8 + k] * calB2[k * 6 + 2 * c + 1];
        }
        wsu[WS_G3P + tid] = pack_rn(g0, g1);
    }
    // C2P / D22P packed copies
    if (tid < 20) {
        int q = tid >> 2, c = tid & 3;
        wsu[WS_C2P + tid] = pack_rn(C2[q * 8 + 2 * c], C2[q * 8 + 2 * c + 1]);
    }
    if (tid < 15) {
        int q = tid / 3, c = tid % 3;
        wsu[WS_D22P + tid] = pack_rn(D22[q * 6 + 2 * c], D22[q * 6 + 2 * c + 1]);
    }
    if (tid < 64) ws[WS_BWF + tid] = KAPPA * bias[8 + tid] * srL[tid];
    if (tid < 8) {
        float acc = 0.f;
        for (int k = 0; k < 8; k++) acc += sEinv[tid * 8 + k] * bias[k];
        ws[WS_G4 + tid] = acc;
    }
    if (tid < 5) ws[WS_BY + tid] = bias[72 + tid];
}

// acc already kappa-scaled: tanh(v) = 1 - 2/(1+2^q). No clamp needed:
// exp2(+big)=inf -> rcp=0 -> +1 ; exp2(-big)=0 -> rcp(1)=1 -> -1.
__device__ __forceinline__ float tanh_scaled(float q) {
    float e = __builtin_amdgcn_exp2f(q);
    return 1.f - 2.f * __builtin_amdgcn_rcpf(1.f + e);
}

__global__ __launch_bounds__(256) void k_main(
    const float* __restrict__ xg, const float* __restrict__ ug,
    const float* __restrict__ ws, float* __restrict__ out, int B)
{
    int t = blockIdx.x * blockDim.x + threadIdx.x;
    int BH = B >> 1;
    if (t >= BH) return;
    const int r0 = t, r1 = t + BH;   // two coalesced halves

    const unsigned* wsu = (const unsigned*)ws;

    // load + pack x,u for both rows
    unsigned xhA[4], uhA[3], xhB[4], uhB[3];
    {
        const float4* xpA = reinterpret_cast<const float4*>(xg + (size_t)r0 * 8);
        const float4* xpB = reinterpret_cast<const float4*>(xg + (size_t)r1 * 8);
        float4 a0 = xpA[0], a1 = xpA[1], b0 = xpB[0], b1 = xpB[1];
        xhA[0] = pack_rn(a0.x, a0.y); xhA[1] = pack_rn(a0.z, a0.w);
        xhA[2] = pack_rn(a1.x, a1.y); xhA[3] = pack_rn(a1.z, a1.w);
        xhB[0] = pack_rn(b0.x, b0.y); xhB[1] = pack_rn(b0.z, b0.w);
        xhB[2] = pack_rn(b1.x, b1.y); xhB[3] = pack_rn(b1.z, b1.w);
        const float2* upA = reinterpret_cast<const float2*>(ug + (size_t)r0 * 6);
        const float2* upB = reinterpret_cast<const float2*>(ug + (size_t)r1 * 6);
        float2 c0 = upA[0], c1 = upA[1], c2 = upA[2];
        float2 d0 = upB[0], d1 = upB[1], d2 = upB[2];
        uhA[0] = pack_rn(c0.x, c0.y); uhA[1] = pack_rn(c1.x, c1.y); uhA[2] = pack_rn(c2.x, c2.y);
        uhB[0] = pack_rn(d0.x, d0.y); uhB[1] = pack_rn(d1.x, d1.y); uhB[2] = pack_rn(d2.x, d2.y);
    }

    // v0 pairs (kappa-scaled), packed; both rows share each constant read
    unsigned svA[32], svB[32];
    #pragma unroll
    for (int k = 0; k < 32; k++) {
        float be = ws[WS_BWF + 2 * k], bo = ws[WS_BWF + 2 * k + 1];
        float a0 = be, a1 = bo, b0 = be, b1 = bo;
        #pragma unroll
        for (int c = 0; c < 4; c++) {
            unsigned cE = wsu[WS_V0C + (2 * k) * 8 + c];
            unsigned cO = wsu[WS_V0C + (2 * k + 1) * 8 + c];
            a0 = dot2(cE, xhA[c], a0); b0 = dot2(cE, xhB[c], b0);
            a1 = dot2(cO, xhA[c], a1); b1 = dot2(cO, xhB[c], b1);
        }
        #pragma unroll
        for (int c = 0; c < 3; c++) {
            unsigned cE = wsu[WS_V0C + (2 * k) * 8 + 4 + c];
            unsigned cO = wsu[WS_V0C + (2 * k + 1) * 8 + 4 + c];
            a0 = dot2(cE, uhA[c], a0); b0 = dot2(cE, uhB[c], b0);
            a1 = dot2(cO, uhA[c], a1); b1 = dot2(cO, uhB[c], b1);
        }
        svA[k] = pack_rn(a0, a1); svB[k] = pack_rn(b0, b1);
    }

    // x/u parts of outputs
    float hA[8], hB[8];
    #pragma unroll
    for (int a = 0; a < 8; a++) {
        float g4 = ws[WS_G4 + a];
        float accA = g4, accB = g4;
        #pragma unroll
        for (int c = 0; c < 4; c++) {
            unsigned g = wsu[WS_G1P + a * 4 + c];
            accA = dot2(g, xhA[c], accA); accB = dot2(g, xhB[c], accB);
        }
        #pragma unroll
        for (int c = 0; c < 3; c++) {
            unsigned g = wsu[WS_G3P + a * 3 + c];
            accA = dot2(g, uhA[c], accA); accB = dot2(g, uhB[c], accB);
        }
        hA[a] = accA; hB[a] = accB;
    }
    float yA[5], yB[5];
    #pragma unroll
    for (int q = 0; q < 5; q++) {
        float by = ws[WS_BY + q];
        float accA = by, accB = by;
        #pragma unroll
        for (int c = 0; c < 4; c++) {
            unsigned g = wsu[WS_C2P + q * 4 + c];
            accA = dot2(g, xhA[c], accA); accB = dot2(g, xhB[c], accB);
        }
        #pragma unroll
        for (int c = 0; c < 3; c++) {
            unsigned g = wsu[WS_D22P + q * 3 + c];
            accA = dot2(g, uhA[c], accA); accB = dot2(g, uhB[c], accB);
        }
        yA[q] = accA; yB[q] = accB;
    }

    // triangular tanh scan, two rows of the batch per thread, two neuron
    // rows (2k,2k+1) per pair-slot. Dual accumulators per neuron row +
    // two batch rows = 4+ independent dot2 chains in flight.
    #pragma unroll
    for (int k = 0; k < 32; k++) {
        unsigned curA = svA[k], curB = svB[k];

        float aE = lo_f(curA), aO = 0.f, bE = lo_f(curB), bO = 0.f;
        #pragma unroll
        for (int p = 0; p < k; p += 2) {
            unsigned c = wsu[WS_DTT2 + (2 * k) * 32 + p];
            aE = dot2(c, svA[p], aE); bE = dot2(c, svB[p], bE);
        }
        #pragma unroll
        for (int p = 1; p < k; p += 2) {
            unsigned c = wsu[WS_DTT2 + (2 * k) * 32 + p];
            aO = dot2(c, svA[p], aO); bO = dot2(c, svB[p], bO);
        }
        float weA = tanh_scaled(aE + aO);
        float weB = tanh_scaled(bE + bO);

        float cE = (float)__builtin_bit_cast(h2, curA).y, cO = 0.f;
        float dE = (float)__builtin_bit_cast(h2, curB).y, dO = 0.f;
        #pragma unroll
        for (int p = 0; p < k; p += 2) {
            unsigned c = wsu[WS_DTT2 + (2 * k + 1) * 32 + p];
            cE = dot2(c, svA[p], cE); dE = dot2(c, svB[p], dE);
        }
        #pragma unroll
        for (int p = 1; p < k; p += 2) {
            unsigned c = wsu[WS_DTT2 + (2 * k + 1) * 32 + p];
            cO = dot2(c, svA[p], cO); dO = dot2(c, svB[p], dO);
        }
        float dcoef = lo_f(wsu[WS_DTT2 + (2 * k + 1) * 32 + k]);  // j = 2k term
        float woA = tanh_scaled(cE + cO + dcoef * weA);
        float woB = tanh_scaled(dE + dO + dcoef * weB);

        svA[k] = pack_rn(weA, woA); svB[k] = pack_rn(weB, woB);
    }

    // w contributions to outputs
    #pragma unroll
    for (int a = 0; a < 8; a++) {
        float accA = hA[a], accB = hB[a];
        #pragma unroll
        for (int p = 0; p < 32; p++) {
            unsigned g = wsu[WS_G2P + a * 32 + p];
            accA = dot2(g, svA[p], accA); accB = dot2(g, svB[p], accB);
        }
        hA[a] = accA; hB[a] = accB;
    }
    float4* hpA = reinterpret_cast<float4*>(out + (size_t)r0 * 8);
    hpA[0] = make_float4(hA[0], hA[1], hA[2], hA[3]);
    hpA[1] = make_float4(hA[4], hA[5], hA[6], hA[7]);
    float4* hpB = reinterpret_cast<float4*>(out + (size_t)r1 * 8);
    hpB[0] = make_float4(hB[0], hB[1], hB[2], hB[3]);
    hpB[1] = make_float4(hB[4], hB[5], hB[6], hB[7]);

    float* ypA = out + (size_t)B * 8 + (size_t)r0 * 5;
    float* ypB = out + (size_t)B * 8 + (size_t)r1 * 5;
    #pragma unroll
    for (int q = 0; q < 5; q++) {
        float accA = yA[q], accB = yB[q];
        #pragma unroll
        for (int p = 0; p < 32; p++) {
            unsigned g = wsu[WS_D21P + q * 32 + p];
            accA = dot2(g, svA[p], accA); accB = dot2(g, svB[p], accB);
        }
        ypA[q] = accA; ypB[q] = accB;
    }
}

extern "C" void kernel_launch(void* const* d_in, const int* in_sizes, int n_in,
                              void* d_out, int out_size, void* d_ws, size_t ws_size,
                              hipStream_t stream) {
    const float* x      = (const float*)d_in[0];
    const float* u      = (const float*)d_in[1];
    const float* X      = (const float*)d_in[2];
    const float* calB2  = (const float*)d_in[3];
    const float* C2     = (const float*)d_in[4];
    const float* calD12 = (const float*)d_in[5];
    const float* D21    = (const float*)d_in[6];
    const float* D22    = (const float*)d_in[7];
    const float* Y1     = (const float*)d_in[8];
    const float* bias   = (const float*)d_in[9];
    float* ws  = (float*)d_ws;
    float* out = (float*)d_out;
    int B = in_sizes[0] / 8;
    int BH = B >> 1;

    k_prep<<<1, 512, 0, stream>>>(X, calB2, calD12, C2, D21, D22, Y1, bias, ws);
    k_main<<<(BH + 255) / 256, 256, 0, stream>>>(x, u, ws, out, B);
}